// Round 4
// baseline (87.722 us; speedup 1.0000x reference)
//
#include <hip/hip_runtime.h>

#define N_ATOMS  4096
#define N_RBF    16
#define N_HIDDEN 64
#define NTHREADS 256
#define WPB      4                        // waves per block
#define TI       2                        // atoms per wave (share j-reads)
#define NBLOCKS  (N_ATOMS / (WPB * TI))   // 512
#define QCAP     256                      // per-atom candidate queue

__global__ void zero_out_kernel(float* __restrict__ out) {
    if (threadIdx.x == 0 && blockIdx.x == 0) out[0] = 0.0f;
}

// One pair's RBF contribution into f[0..15]. d2=1e8 sentinel -> exactly 0.
__device__ __forceinline__ void accum_rbf(float d2, float (&f)[N_RBF]) {
    const float d  = sqrtf(d2);
    const float sm = 0.5f + 0.5f * __cosf(0.62831853071795865f * d); // 0.5*(1+cos(pi*d/5))
    #pragma unroll
    for (int k = 0; k < N_RBF; ++k) {
        const float t = d - (0.5f + 0.3f * (float)k);   // centers 0.5+0.3k
        f[k] += sm * __expf(-20.48f * t * t);           // 1/(2*eta^2) = 20.48
    }
}

__device__ __forceinline__ int wave_prefix(unsigned long long m) {
    return __builtin_amdgcn_mbcnt_hi((unsigned)(m >> 32),
            __builtin_amdgcn_mbcnt_lo((unsigned)m, 0u));
}

__global__ __launch_bounds__(NTHREADS) void fused_sr_kernel(
    const float* __restrict__ pos,   // (N,3)
    const float* __restrict__ W1,    // (16,64)
    const float* __restrict__ b1,    // (64,)
    const float* __restrict__ W2,    // (64,64)
    const float* __restrict__ b2,    // (64,)
    const float* __restrict__ W3,    // (64,1)
    const float* __restrict__ b3,    // (1,)
    float* __restrict__ out)         // scalar
{
    __shared__ __align__(16) float4 sp[N_ATOMS];          // 64 KB
    __shared__ float qd[WPB][TI][QCAP];                   // 8 KB d^2 queues
    __shared__ __align__(16) float h1buf[WPB][N_HIDDEN];  // 1 KB
    __shared__ float ered[WPB];
    // total ~73 KB -> 2 blocks/CU, 8 waves/CU

    const int tid = threadIdx.x;

    for (int idx = tid; idx < N_ATOMS; idx += NTHREADS) {
        sp[idx] = make_float4(pos[idx * 3 + 0], pos[idx * 3 + 1], pos[idx * 3 + 2], 0.0f);
    }
    __syncthreads();

    const int lane = tid & 63;
    const int wib  = tid >> 6;
    const int gw   = blockIdx.x * WPB + wib;   // 0..2047
    const int i0   = gw * TI;

    const float4 pa = sp[i0];
    const float4 pb = sp[i0 + 1];

    // ---- branch-free compaction sweep: one float4 j-read feeds 2 atoms ----
    int cnt0 = 0, cnt1 = 0;
    #pragma unroll 8
    for (int j0 = 0; j0 < N_ATOMS; j0 += 64) {
        const float4 pj = sp[j0 + lane];
        {   // atom A
            const float dx = pa.x - pj.x, dy = pa.y - pj.y, dz = pa.z - pj.z;
            const float d2 = fmaf(dx, dx, fmaf(dy, dy, dz * dz));
            const bool act = (d2 < 25.0f) && (d2 > 1e-12f);
            const unsigned long long m = __ballot(act);
            int widx = cnt0 + wave_prefix(m);
            widx = widx < QCAP ? widx : QCAP - 1;
            if (act) qd[wib][0][widx] = d2;          // predicated, stride-1
            cnt0 += (int)__popcll(m);
        }
        {   // atom B
            const float dx = pb.x - pj.x, dy = pb.y - pj.y, dz = pb.z - pj.z;
            const float d2 = fmaf(dx, dx, fmaf(dy, dy, dz * dz));
            const bool act = (d2 < 25.0f) && (d2 > 1e-12f);
            const unsigned long long m = __ballot(act);
            int widx = cnt1 + wave_prefix(m);
            widx = widx < QCAP ? widx : QCAP - 1;
            if (act) qd[wib][1][widx] = d2;
            cnt1 += (int)__popcll(m);
        }
    }

    // ---- drain: full-lane RBF evaluation, per atom ----
    float f[TI][N_RBF];
    #pragma unroll
    for (int a = 0; a < TI; ++a)
        #pragma unroll
        for (int k = 0; k < N_RBF; ++k) f[a][k] = 0.0f;

    for (int b = 0; b < cnt0; b += 64) {
        const int q = b + lane;
        accum_rbf((q < cnt0) ? qd[wib][0][q] : 1e8f, f[0]);
    }
    for (int b = 0; b < cnt1; b += 64) {
        const int q = b + lane;
        accum_rbf((q < cnt1) ? qd[wib][1][q] : 1e8f, f[1]);
    }

    // ---- per-atom MLP (lane h <-> hidden unit h) ----
    float energy = 0.0f;
    #pragma unroll
    for (int a = 0; a < TI; ++a) {
        #pragma unroll
        for (int k = 0; k < N_RBF; ++k) {
            #pragma unroll
            for (int off = 32; off > 0; off >>= 1)
                f[a][k] += __shfl_xor(f[a][k], off, 64);
        }

        float a1 = b1[lane];
        #pragma unroll
        for (int k = 0; k < N_RBF; ++k)
            a1 = fmaf(f[a][k], W1[k * N_HIDDEN + lane], a1);
        const float h1 = a1 / (1.0f + __expf(-a1));   // silu

        h1buf[wib][lane] = h1;   // same-wave LDS exchange (DS ops in-order)
        float a2 = b2[lane];
        #pragma unroll
        for (int k = 0; k < N_HIDDEN; k += 4) {
            const float4 hv = *reinterpret_cast<const float4*>(&h1buf[wib][k]);
            a2 = fmaf(hv.x, W2[(k + 0) * N_HIDDEN + lane], a2);
            a2 = fmaf(hv.y, W2[(k + 1) * N_HIDDEN + lane], a2);
            a2 = fmaf(hv.z, W2[(k + 2) * N_HIDDEN + lane], a2);
            a2 = fmaf(hv.w, W2[(k + 3) * N_HIDDEN + lane], a2);
        }
        const float h2 = a2 / (1.0f + __expf(-a2));   // silu

        energy += h2 * W3[lane];
    }

    // ---- wave reduce -> block reduce -> one atomic per block ----
    #pragma unroll
    for (int off = 32; off > 0; off >>= 1)
        energy += __shfl_xor(energy, off, 64);
    if (lane == 0) ered[wib] = energy;
    __syncthreads();
    if (tid == 0) {
        float e = 0.0f;
        #pragma unroll
        for (int w = 0; w < WPB; ++w) e += ered[w];
        atomicAdd(out, e + (float)(WPB * TI) * b3[0]);
    }
}

extern "C" void kernel_launch(void* const* d_in, const int* in_sizes, int n_in,
                              void* d_out, int out_size, void* d_ws, size_t ws_size,
                              hipStream_t stream) {
    const float* pos = (const float*)d_in[0];
    const float* W1  = (const float*)d_in[1];
    const float* b1  = (const float*)d_in[2];
    const float* W2  = (const float*)d_in[3];
    const float* b2  = (const float*)d_in[4];
    const float* W3  = (const float*)d_in[5];
    const float* b3  = (const float*)d_in[6];
    float* out = (float*)d_out;

    zero_out_kernel<<<1, 64, 0, stream>>>(out);
    fused_sr_kernel<<<NBLOCKS, NTHREADS, 0, stream>>>(pos, W1, b1, W2, b2, W3, b3, out);
}

// Round 5
// 84.084 us; speedup vs baseline: 1.0433x; 1.0433x over previous
//
#include <hip/hip_runtime.h>

#define N_ATOMS  4096
#define N_RBF    16
#define N_HIDDEN 64
#define NTHREADS 512
#define WPB      8        // waves per block, 1 atom per wave
#define NBLOCKS  (N_ATOMS / WPB)   // 512 blocks -> 2 blocks/CU, 16 waves/CU
#define QCAP     256      // per-wave candidate queue (max neighbors ~190)

__global__ void zero_out_kernel(float* __restrict__ out) {
    if (threadIdx.x == 0 && blockIdx.x == 0) out[0] = 0.0f;
}

// One pair's RBF contribution into f[0..15]. d2=1e8 sentinel -> exactly 0.
__device__ __forceinline__ void accum_rbf(float d2, float (&f)[N_RBF]) {
    const float d  = sqrtf(d2);
    const float sm = 0.5f + 0.5f * __cosf(0.62831853071795865f * d); // 0.5*(1+cos(pi*d/5))
    #pragma unroll
    for (int k = 0; k < N_RBF; ++k) {
        const float t = d - (0.5f + 0.3f * (float)k);   // centers 0.5+0.3k
        f[k] += sm * __expf(-20.48f * t * t);           // 1/(2*eta^2) = 20.48
    }
}

__device__ __forceinline__ int wave_prefix(unsigned long long m) {
    return __builtin_amdgcn_mbcnt_hi((unsigned)(m >> 32),
            __builtin_amdgcn_mbcnt_lo((unsigned)m, 0u));
}

__global__ __launch_bounds__(NTHREADS, 4) void fused_sr_kernel(
    const float* __restrict__ pos,   // (N,3)
    const float* __restrict__ W1,    // (16,64)
    const float* __restrict__ b1,    // (64,)
    const float* __restrict__ W2,    // (64,64)
    const float* __restrict__ b2,    // (64,)
    const float* __restrict__ W3,    // (64,1)
    const float* __restrict__ b3,    // (1,)
    float* __restrict__ out)         // scalar
{
    __shared__ __align__(16) float4 sp[N_ATOMS];          // 64 KB: xyz + pad
    __shared__ float qd[WPB][QCAP];                       // 8 KB d^2 queues
    __shared__ __align__(16) float h1buf[WPB][N_HIDDEN];  // 2 KB
    __shared__ float ered[WPB];
    // ~74 KB -> 2 blocks/CU (148 of 160 KB), 16 waves/CU (4/SIMD)

    const int tid = threadIdx.x;

    for (int idx = tid; idx < N_ATOMS; idx += NTHREADS) {
        sp[idx] = make_float4(pos[idx * 3 + 0], pos[idx * 3 + 1], pos[idx * 3 + 2], 0.0f);
    }
    __syncthreads();

    const int lane = tid & 63;
    const int wib  = tid >> 6;
    const int i    = blockIdx.x * WPB + wib;   // this wave's atom

    const float4 pi4 = sp[i];                  // wave-uniform
    const float xi = pi4.x, yi = pi4.y, zi = pi4.z;

    // ---- branch-free compaction sweep: one ds_read_b128 per j-visit ----
    int cnt = 0;
    #pragma unroll 8
    for (int j0 = 0; j0 < N_ATOMS; j0 += 64) {
        const float4 pj = sp[j0 + lane];
        const float dx = xi - pj.x;
        const float dy = yi - pj.y;
        const float dz = zi - pj.z;
        const float d2 = fmaf(dx, dx, fmaf(dy, dy, dz * dz));
        const bool act = (d2 < 25.0f) && (d2 > 1e-12f);  // 1e-6 < d < 5
        const unsigned long long m = __ballot(act);
        int widx = cnt + wave_prefix(m);
        widx = widx < QCAP ? widx : QCAP - 1;            // overflow clamp (safety)
        if (act) qd[wib][widx] = d2;                     // predicated, stride-1
        cnt += (int)__popcll(m);
    }

    // ---- drain: full-lane RBF evaluation ----
    float f[N_RBF];
    #pragma unroll
    for (int k = 0; k < N_RBF; ++k) f[k] = 0.0f;
    for (int b = 0; b < cnt; b += 64) {
        const int q = b + lane;
        accum_rbf((q < cnt) ? qd[wib][q] : 1e8f, f);
    }

    // ---- butterfly allreduce of 16 feature partials ----
    #pragma unroll
    for (int k = 0; k < N_RBF; ++k) {
        #pragma unroll
        for (int off = 32; off > 0; off >>= 1)
            f[k] += __shfl_xor(f[k], off, 64);
    }

    // ---- MLP: lane h <-> hidden unit h ----
    float a1 = b1[lane];
    #pragma unroll
    for (int k = 0; k < N_RBF; ++k)
        a1 = fmaf(f[k], W1[k * N_HIDDEN + lane], a1);
    const float h1 = a1 / (1.0f + __expf(-a1));   // silu

    h1buf[wib][lane] = h1;   // same-wave LDS exchange (DS ops in-order)
    float a2 = b2[lane];
    #pragma unroll
    for (int k = 0; k < N_HIDDEN; k += 4) {
        const float4 hv = *reinterpret_cast<const float4*>(&h1buf[wib][k]);
        a2 = fmaf(hv.x, W2[(k + 0) * N_HIDDEN + lane], a2);
        a2 = fmaf(hv.y, W2[(k + 1) * N_HIDDEN + lane], a2);
        a2 = fmaf(hv.z, W2[(k + 2) * N_HIDDEN + lane], a2);
        a2 = fmaf(hv.w, W2[(k + 3) * N_HIDDEN + lane], a2);
    }
    const float h2 = a2 / (1.0f + __expf(-a2));   // silu

    // ---- energy: wave reduce -> block reduce -> one atomic per block ----
    float energy = h2 * W3[lane];
    #pragma unroll
    for (int off = 32; off > 0; off >>= 1)
        energy += __shfl_xor(energy, off, 64);
    if (lane == 0) ered[wib] = energy;
    __syncthreads();
    if (tid == 0) {
        float e = 0.0f;
        #pragma unroll
        for (int w = 0; w < WPB; ++w) e += ered[w];
        atomicAdd(out, e + (float)WPB * b3[0]);
    }
}

extern "C" void kernel_launch(void* const* d_in, const int* in_sizes, int n_in,
                              void* d_out, int out_size, void* d_ws, size_t ws_size,
                              hipStream_t stream) {
    const float* pos = (const float*)d_in[0];
    const float* W1  = (const float*)d_in[1];
    const float* b1  = (const float*)d_in[2];
    const float* W2  = (const float*)d_in[3];
    const float* b2  = (const float*)d_in[4];
    const float* W3  = (const float*)d_in[5];
    const float* b3  = (const float*)d_in[6];
    float* out = (float*)d_out;

    zero_out_kernel<<<1, 64, 0, stream>>>(out);
    fused_sr_kernel<<<NBLOCKS, NTHREADS, 0, stream>>>(pos, W1, b1, W2, b2, W3, b3, out);
}